// Round 12
// baseline (33.751 us; speedup 1.0000x reference)
//
#include <hip/hip_runtime.h>
#include <hip/hip_bf16.h>
#include <math.h>

#define BB 8
#define SS 2048
#define HH 768
#define NN 512
#define MAXW 30
#define SPW 8            // spans (waves) per block
#define CROWS 24         // rows per LDS chunk (double-buffered)

typedef float f32x4 __attribute__((ext_vector_type(4)));

// fp32 -> bf16 (RNE) raw
static __device__ __forceinline__ unsigned short f2bf(float f) {
    union { float f; unsigned int u; } v; v.f = f;
    unsigned int r = (v.u + 0x7FFFu + ((v.u >> 16) & 1u)) >> 16;
    return (unsigned short)r;
}
static __device__ __forceinline__ float bflo(unsigned int u) {
    union { unsigned int u; float f; } v; v.u = u << 16; return v.f;
}
static __device__ __forceinline__ float bfhi(unsigned int u) {
    union { unsigned int u; float f; } v; v.u = u & 0xFFFF0000u; return v.f;
}

// ---- Kernel A: per-example counting sort of spans by start (parallel scan) ----
__global__ __launch_bounds__(256) void sort_spans_kernel(
    const int* __restrict__ starts,   // (B, N)
    int*       __restrict__ order)    // (B, N): order[b*N + rank] = span idx
{
    const int b   = blockIdx.x;
    const int tid = threadIdx.x;
    __shared__ int hist[SS];
    __shared__ int wsum[4];

    for (int i = tid; i < SS; i += 256) hist[i] = 0;
    __syncthreads();

    const int* st = starts + b * NN;
    for (int n = tid; n < NN; n += 256) atomicAdd(&hist[st[n]], 1);
    __syncthreads();

    const int base = tid * 8;
    int cnt[8]; int s = 0;
    #pragma unroll
    for (int k = 0; k < 8; ++k) { cnt[k] = hist[base + k]; s += cnt[k]; }

    const int lane = tid & 63, wv = tid >> 6;
    int v = s;
    #pragma unroll
    for (int off = 1; off < 64; off <<= 1) {
        int u = __shfl_up(v, off);
        if (lane >= off) v += u;
    }
    if (lane == 63) wsum[wv] = v;
    __syncthreads();
    int wbase = 0;
    #pragma unroll
    for (int k = 0; k < 4; ++k) wbase += (k < wv) ? wsum[k] : 0;

    int excl = wbase + v - s;
    #pragma unroll
    for (int k = 0; k < 8; ++k) { int c = cnt[k]; hist[base + k] = excl; excl += c; }
    __syncthreads();

    for (int n = tid; n < NN; n += 256) {
        int pos = atomicAdd(&hist[st[n]], 1);
        order[b * NN + pos] = n;
    }
}

// ---- Kernel B: fused single-kernel producer/consumer.
//      8 sorted spans per block (1 wave each). The block's union token window
//      is swept in 24-row chunks: produce = fp32 rows -> score (shfl) + bf16
//      rows into LDS (3 rows/wave, batched loads); ONE barrier per chunk;
//      consume = per-span online softmax from LDS (no shfl, uniform score).
__global__ __launch_bounds__(512, 4) void span_lds_kernel(
    const float* __restrict__ emb,      // (B, S, H)
    const float* __restrict__ w,        // (H)
    const float* __restrict__ bias,     // (1)
    const int*   __restrict__ starts,   // (B, N)
    const int*   __restrict__ lengths,  // (B, N)
    const int*   __restrict__ order,    // (B, N) or nullptr
    float*       __restrict__ out)      // (B, N, 3H)
{
    const int tid  = threadIdx.x;
    const int wv   = tid >> 6;           // 0..7
    const int lane = tid & 63;
    const int bi   = blockIdx.x & 7;     // example <-> XCD
    const int g    = (int)blockIdx.x >> 3;
    const int rank = g * SPW + wv;
    const int n    = order ? order[bi * NN + rank] : rank;
    const int span = bi * NN + n;

    const int start = starts[span];
    const int len   = lengths[span];
    const int end   = start + len;       // inclusive

    __shared__ int s_lo[SPW], s_hi[SPW];
    if (lane == 0) { s_lo[wv] = start; s_hi[wv] = end; }
    __syncthreads();
    int wlo = s_lo[0], whi = s_hi[0];
    #pragma unroll
    for (int k = 1; k < SPW; ++k) { wlo = min(wlo, s_lo[k]); whi = max(whi, s_hi[k]); }

    __shared__ unsigned short s_rows[2][CROWS][HH];   // 72 KiB
    __shared__ float s_scr[2][CROWS];

    const float* eb = emb + (size_t)bi * SS * HH;
    const int h0 = lane * 4;
    float* orow = out + (size_t)span * (3 * HH);

    const f32x4 w0 = *reinterpret_cast<const f32x4*>(w + h0);
    const f32x4 w1 = *reinterpret_cast<const f32x4*>(w + h0 + 256);
    const f32x4 w2 = *reinterpret_cast<const f32x4*>(w + h0 + 512);
    const float bb = bias[0];

    // produce chunk c into buffer buf: rows j = wv, wv+8, wv+16
    auto produce = [&](int c, int buf) {
        const int clo = wlo + c * CROWS;
        f32x4 r0[3], r1[3], r2[3];
        bool vld[3];
        #pragma unroll
        for (int q = 0; q < 3; ++q) {
            const int tok = clo + wv + q * 8;
            vld[q] = (tok <= whi);
            if (vld[q]) {
                const float* rp = eb + (size_t)tok * HH + h0;
                r0[q] = *reinterpret_cast<const f32x4*>(rp);
                r1[q] = *reinterpret_cast<const f32x4*>(rp + 256);
                r2[q] = *reinterpret_cast<const f32x4*>(rp + 512);
            }
        }
        float d[3];
        #pragma unroll
        for (int q = 0; q < 3; ++q) {
            d[q] = vld[q]
                 ? (r0[q][0]*w0[0] + r0[q][1]*w0[1] + r0[q][2]*w0[2] + r0[q][3]*w0[3]
                  + r1[q][0]*w1[0] + r1[q][1]*w1[1] + r1[q][2]*w1[2] + r1[q][3]*w1[3]
                  + r2[q][0]*w2[0] + r2[q][1]*w2[1] + r2[q][2]*w2[2] + r2[q][3]*w2[3])
                 : 0.f;
        }
        #pragma unroll
        for (int off = 32; off; off >>= 1) {
            #pragma unroll
            for (int q = 0; q < 3; ++q) d[q] += __shfl_xor(d[q], off);
        }
        #pragma unroll
        for (int q = 0; q < 3; ++q) {
            if (vld[q]) {
                const int j = wv + q * 8;
                uint2 pa, pb, pc;
                pa.x = (unsigned)f2bf(r0[q][0]) | ((unsigned)f2bf(r0[q][1]) << 16);
                pa.y = (unsigned)f2bf(r0[q][2]) | ((unsigned)f2bf(r0[q][3]) << 16);
                pb.x = (unsigned)f2bf(r1[q][0]) | ((unsigned)f2bf(r1[q][1]) << 16);
                pb.y = (unsigned)f2bf(r1[q][2]) | ((unsigned)f2bf(r1[q][3]) << 16);
                pc.x = (unsigned)f2bf(r2[q][0]) | ((unsigned)f2bf(r2[q][1]) << 16);
                pc.y = (unsigned)f2bf(r2[q][2]) | ((unsigned)f2bf(r2[q][3]) << 16);
                unsigned short* dst = &s_rows[buf][j][0];
                *reinterpret_cast<uint2*>(dst + h0)       = pa;
                *reinterpret_cast<uint2*>(dst + h0 + 256) = pb;
                *reinterpret_cast<uint2*>(dst + h0 + 512) = pc;
                if (lane == 0) s_scr[buf][j] = d[q] + bb;
            }
        }
    };

    float m = -INFINITY, ssum = 0.f;
    float4 a0 = make_float4(0.f, 0.f, 0.f, 0.f), a1 = a0, a2 = a0;

    const int nch = (whi - wlo) / CROWS + 1;   // block-uniform

    produce(0, 0);
    __syncthreads();

    for (int c = 0; c < nch; ++c) {
        const int buf = c & 1;
        if (c + 1 < nch) produce(c + 1, buf ^ 1);

        const int clo = wlo + c * CROWS;
        const int t0  = max(clo, start);
        const int t1  = min(clo + CROWS - 1, end);

        for (int t = t0; t <= t1; ++t) {
            const int j = t - clo;
            const float ds = s_scr[buf][j];              // uniform broadcast
            const unsigned short* src = &s_rows[buf][j][0];
            uint2 cA = *reinterpret_cast<const uint2*>(src + h0);
            uint2 cB = *reinterpret_cast<const uint2*>(src + h0 + 256);
            uint2 cC = *reinterpret_cast<const uint2*>(src + h0 + 512);

            if (ds > m) {                                // wave-uniform
                const float cc = __expf(m - ds);         // first: exp(-inf)=0
                ssum *= cc;
                a0.x *= cc; a0.y *= cc; a0.z *= cc; a0.w *= cc;
                a1.x *= cc; a1.y *= cc; a1.z *= cc; a1.w *= cc;
                a2.x *= cc; a2.y *= cc; a2.z *= cc; a2.w *= cc;
                m = ds;
            }
            const float pt = __expf(ds - m);
            ssum += pt;

            float4 f0, f1, f2;
            f0.x = bflo(cA.x); f0.y = bfhi(cA.x); f0.z = bflo(cA.y); f0.w = bfhi(cA.y);
            f1.x = bflo(cB.x); f1.y = bfhi(cB.x); f1.z = bflo(cB.y); f1.w = bfhi(cB.y);
            f2.x = bflo(cC.x); f2.y = bfhi(cC.x); f2.z = bflo(cC.y); f2.w = bfhi(cC.y);

            a0.x += pt * f0.x; a0.y += pt * f0.y; a0.z += pt * f0.z; a0.w += pt * f0.w;
            a1.x += pt * f1.x; a1.y += pt * f1.y; a1.z += pt * f1.z; a1.w += pt * f1.w;
            a2.x += pt * f2.x; a2.y += pt * f2.y; a2.z += pt * f2.z; a2.w += pt * f2.w;

            if (t == start) {
                __builtin_nontemporal_store(*(const f32x4*)&f0, (f32x4*)(orow + h0));
                __builtin_nontemporal_store(*(const f32x4*)&f1, (f32x4*)(orow + h0 + 256));
                __builtin_nontemporal_store(*(const f32x4*)&f2, (f32x4*)(orow + h0 + 512));
            }
            if (t == end) {
                __builtin_nontemporal_store(*(const f32x4*)&f0, (f32x4*)(orow + HH + h0));
                __builtin_nontemporal_store(*(const f32x4*)&f1, (f32x4*)(orow + HH + h0 + 256));
                __builtin_nontemporal_store(*(const f32x4*)&f2, (f32x4*)(orow + HH + h0 + 512));
            }
        }
        __syncthreads();   // produce(c+1) done AND buf fully consumed
    }

    const float inv = 1.f / ssum;
    a0.x *= inv; a0.y *= inv; a0.z *= inv; a0.w *= inv;
    a1.x *= inv; a1.y *= inv; a1.z *= inv; a1.w *= inv;
    a2.x *= inv; a2.y *= inv; a2.z *= inv; a2.w *= inv;
    __builtin_nontemporal_store(*(const f32x4*)&a0, (f32x4*)(orow + 2 * HH + h0));
    __builtin_nontemporal_store(*(const f32x4*)&a1, (f32x4*)(orow + 2 * HH + h0 + 256));
    __builtin_nontemporal_store(*(const f32x4*)&a2, (f32x4*)(orow + 2 * HH + h0 + 512));
}

extern "C" void kernel_launch(void* const* d_in, const int* in_sizes, int n_in,
                              void* d_out, int out_size, void* d_ws, size_t ws_size,
                              hipStream_t stream) {
    const float* emb     = (const float*)d_in[0];
    const float* w       = (const float*)d_in[1];
    const float* bias    = (const float*)d_in[2];
    const int*   starts  = (const int*)d_in[3];
    const int*   lengths = (const int*)d_in[4];
    float*       out     = (float*)d_out;

    int* order = nullptr;
    if (ws_size >= (size_t)(BB * NN * sizeof(int))) {
        order = (int*)d_ws;
        sort_spans_kernel<<<dim3(BB), dim3(256), 0, stream>>>(starts, order);
    }

    span_lds_kernel<<<dim3(BB * NN / SPW), dim3(512), 0, stream>>>(
        emb, w, bias, starts, lengths, order, out);
}

// Round 13
// 30.802 us; speedup vs baseline: 1.0957x; 1.0957x over previous
//
#include <hip/hip_runtime.h>
#include <hip/hip_bf16.h>
#include <math.h>

#define BB 8
#define SS 2048
#define HH 768
#define NN 512
#define MAXW 30

typedef float f32x4 __attribute__((ext_vector_type(4)));

// fp32 -> bf16 (RNE) as raw ushort
static __device__ __forceinline__ unsigned short f2bf(float f) {
    union { float f; unsigned int u; } v; v.f = f;
    unsigned int r = (v.u + 0x7FFFu + ((v.u >> 16) & 1u)) >> 16;
    return (unsigned short)r;
}
static __device__ __forceinline__ float bflo(unsigned int u) {
    union { unsigned int u; float f; } v; v.u = u << 16; return v.f;
}
static __device__ __forceinline__ float bfhi(unsigned int u) {
    union { unsigned int u; float f; } v; v.u = u & 0xFFFF0000u; return v.f;
}

// ---- Kernel 1: conv (1024 blocks) + fused per-example counting sort (8 blocks).
//      conv: fp32 rows (nontemporal) -> bf16 copy + token scores. XCD-pinned.
__global__ __launch_bounds__(256) void prep_kernel(
    const float* __restrict__ emb,      // (B, S, H)
    const float* __restrict__ w,        // (H)
    const float* __restrict__ bias,     // (1)
    const int*   __restrict__ starts,   // (B, N)
    unsigned short* __restrict__ ebf,   // (B, S, H) bf16
    float*       __restrict__ scores,   // (B*S)
    int*         __restrict__ order)    // (B*N)
{
    const int tid = threadIdx.x;

    if ((int)blockIdx.x < 1024) {
        // ---------------- conv part ----------------
        const int wv   = tid >> 6;
        const int lane = tid & 63;
        const int bi   = blockIdx.x & 7;            // example <-> XCD
        const int g    = (int)blockIdx.x >> 3;      // 0..127
        const int t0   = g * 16 + wv * 4;           // 4 rows per wave

        const float* eb = emb + (size_t)bi * SS * HH;
        unsigned short* ob = ebf + (size_t)bi * SS * HH;

        const int h0 = lane * 4;
        const f32x4 w0 = *reinterpret_cast<const f32x4*>(w + h0);
        const f32x4 w1 = *reinterpret_cast<const f32x4*>(w + h0 + 256);
        const f32x4 w2 = *reinterpret_cast<const f32x4*>(w + h0 + 512);
        const float bb = bias[0];

        #pragma unroll
        for (int k = 0; k < 4; ++k) {
            const int t = t0 + k;
            const float* rp = eb + (size_t)t * HH;
            // nontemporal: don't displace ebf lines being written to L2
            f32x4 v0 = __builtin_nontemporal_load(reinterpret_cast<const f32x4*>(rp + h0));
            f32x4 v1 = __builtin_nontemporal_load(reinterpret_cast<const f32x4*>(rp + h0 + 256));
            f32x4 v2 = __builtin_nontemporal_load(reinterpret_cast<const f32x4*>(rp + h0 + 512));

            float d = v0[0]*w0[0] + v0[1]*w0[1] + v0[2]*w0[2] + v0[3]*w0[3]
                    + v1[0]*w1[0] + v1[1]*w1[1] + v1[2]*w1[2] + v1[3]*w1[3]
                    + v2[0]*w2[0] + v2[1]*w2[1] + v2[2]*w2[2] + v2[3]*w2[3];
            #pragma unroll
            for (int off = 32; off; off >>= 1) d += __shfl_xor(d, off);

            uint2 pa, pb, pc;
            pa.x = (unsigned)f2bf(v0[0]) | ((unsigned)f2bf(v0[1]) << 16);
            pa.y = (unsigned)f2bf(v0[2]) | ((unsigned)f2bf(v0[3]) << 16);
            pb.x = (unsigned)f2bf(v1[0]) | ((unsigned)f2bf(v1[1]) << 16);
            pb.y = (unsigned)f2bf(v1[2]) | ((unsigned)f2bf(v1[3]) << 16);
            pc.x = (unsigned)f2bf(v2[0]) | ((unsigned)f2bf(v2[1]) << 16);
            pc.y = (unsigned)f2bf(v2[2]) | ((unsigned)f2bf(v2[3]) << 16);

            unsigned short* op = ob + (size_t)t * HH;
            *reinterpret_cast<uint2*>(op + h0)       = pa;
            *reinterpret_cast<uint2*>(op + h0 + 256) = pb;
            *reinterpret_cast<uint2*>(op + h0 + 512) = pc;

            if (lane == 0) scores[bi * SS + t] = d + bb;
        }
    } else {
        // ---------------- counting sort part ----------------
        const int b = blockIdx.x - 1024;
        __shared__ int hist[SS];
        __shared__ int wsum[4];

        for (int i = tid; i < SS; i += 256) hist[i] = 0;
        __syncthreads();

        const int* st = starts + b * NN;
        for (int n = tid; n < NN; n += 256) atomicAdd(&hist[st[n]], 1);
        __syncthreads();

        const int base = tid * 8;
        int cnt[8]; int s = 0;
        #pragma unroll
        for (int k = 0; k < 8; ++k) { cnt[k] = hist[base + k]; s += cnt[k]; }

        const int lane = tid & 63, wv = tid >> 6;
        int v = s;
        #pragma unroll
        for (int off = 1; off < 64; off <<= 1) {
            int u = __shfl_up(v, off);
            if (lane >= off) v += u;
        }
        if (lane == 63) wsum[wv] = v;
        __syncthreads();
        int wbase = 0;
        #pragma unroll
        for (int k = 0; k < 4; ++k) wbase += (k < wv) ? wsum[k] : 0;

        int excl = wbase + v - s;
        #pragma unroll
        for (int k = 0; k < 8; ++k) { int c = cnt[k]; hist[base + k] = excl; excl += c; }
        __syncthreads();

        for (int n = tid; n < NN; n += 256) {
            int pos = atomicAdd(&hist[st[n]], 1);
            order[b * NN + pos] = n;
        }
    }
}

// ---- Kernel 2: one wave per span, DESCENDING sorted start order (LRU-match).
//      Softmax from precomputed scores, bf16 row sweep, nontemporal out stores.
__global__ __launch_bounds__(256) void span_bf16_kernel(
    const unsigned short* __restrict__ ebf,   // (B, S, H) bf16
    const float* __restrict__ scores,         // (B*S)
    const int*   __restrict__ starts,         // (B, N)
    const int*   __restrict__ lengths,        // (B, N)
    const int*   __restrict__ order,          // (B, N)
    float*       __restrict__ out)            // (B, N, 3H)
{
    const int tid  = threadIdx.x;
    const int wv   = tid >> 6;
    const int lane = tid & 63;
    const int bi   = blockIdx.x & 7;          // example <-> XCD
    const int r    = ((int)blockIdx.x >> 3) * 4 + wv;   // 0..511
    const int rank = NN - 1 - r;              // descending starts
    const int n    = order ? order[bi * NN + rank] : r;
    const int span = bi * NN + n;

    const int start = starts[span];
    const int len   = lengths[span];          // valid t = 0..len (<= 29)

    // ---- softmax up-front: lane t holds p_t ----
    float sc = (lane <= len) ? scores[bi * SS + start + lane] : -INFINITY;
    float m = sc;
    #pragma unroll
    for (int off = 32; off; off >>= 1) m = fmaxf(m, __shfl_xor(m, off));
    float e = (lane <= len) ? __expf(sc - m) : 0.f;
    float sum = e;
    #pragma unroll
    for (int off = 32; off; off >>= 1) sum += __shfl_xor(sum, off);
    const float p = e / sum;

    const unsigned short* rb = ebf + (size_t)bi * SS * HH + (size_t)start * HH;
    const int h0 = lane * 4;
    float* orow = out + (size_t)span * (3 * HH);

    float4 a0 = make_float4(0.f, 0.f, 0.f, 0.f), a1 = a0, a2 = a0;

    // 2-deep prefetch pipeline; no duplicate tail loads
    uint2 cA = *reinterpret_cast<const uint2*>(rb + h0);
    uint2 cB = *reinterpret_cast<const uint2*>(rb + h0 + 256);
    uint2 cC = *reinterpret_cast<const uint2*>(rb + h0 + 512);
    uint2 xA, xB, xC;
    if (len >= 1) {
        const unsigned short* rp1 = rb + HH;
        xA = *reinterpret_cast<const uint2*>(rp1 + h0);
        xB = *reinterpret_cast<const uint2*>(rp1 + h0 + 256);
        xC = *reinterpret_cast<const uint2*>(rp1 + h0 + 512);
    } else { xA = cA; xB = cB; xC = cC; }

    for (int t = 0; t <= len; ++t) {
        uint2 yA, yB, yC;
        if (t + 2 <= len) {
            const unsigned short* rp2 = rb + (size_t)(t + 2) * HH;
            yA = *reinterpret_cast<const uint2*>(rp2 + h0);
            yB = *reinterpret_cast<const uint2*>(rp2 + h0 + 256);
            yC = *reinterpret_cast<const uint2*>(rp2 + h0 + 512);
        } else { yA = cA; yB = cB; yC = cC; }

        const float pt = __shfl(p, t);

        float4 f0, f1, f2;
        f0.x = bflo(cA.x); f0.y = bfhi(cA.x); f0.z = bflo(cA.y); f0.w = bfhi(cA.y);
        f1.x = bflo(cB.x); f1.y = bfhi(cB.x); f1.z = bflo(cB.y); f1.w = bfhi(cB.y);
        f2.x = bflo(cC.x); f2.y = bfhi(cC.x); f2.z = bflo(cC.y); f2.w = bfhi(cC.y);

        a0.x += pt * f0.x; a0.y += pt * f0.y; a0.z += pt * f0.z; a0.w += pt * f0.w;
        a1.x += pt * f1.x; a1.y += pt * f1.y; a1.z += pt * f1.z; a1.w += pt * f1.w;
        a2.x += pt * f2.x; a2.y += pt * f2.y; a2.z += pt * f2.z; a2.w += pt * f2.w;

        if (t == 0) {                    // start row (streaming store)
            __builtin_nontemporal_store(*(const f32x4*)&f0, (f32x4*)(orow + h0));
            __builtin_nontemporal_store(*(const f32x4*)&f1, (f32x4*)(orow + h0 + 256));
            __builtin_nontemporal_store(*(const f32x4*)&f2, (f32x4*)(orow + h0 + 512));
        }
        if (t == len) {                  // end row
            __builtin_nontemporal_store(*(const f32x4*)&f0, (f32x4*)(orow + HH + h0));
            __builtin_nontemporal_store(*(const f32x4*)&f1, (f32x4*)(orow + HH + h0 + 256));
            __builtin_nontemporal_store(*(const f32x4*)&f2, (f32x4*)(orow + HH + h0 + 512));
        }

        cA = xA; cB = xB; cC = xC;
        xA = yA; xB = yB; xC = yC;
    }

    __builtin_nontemporal_store(*(const f32x4*)&a0, (f32x4*)(orow + 2 * HH + h0));
    __builtin_nontemporal_store(*(const f32x4*)&a1, (f32x4*)(orow + 2 * HH + h0 + 256));
    __builtin_nontemporal_store(*(const f32x4*)&a2, (f32x4*)(orow + 2 * HH + h0 + 512));
}

// ---- Fallback (tiny ws): R4's fused fp32 single-pass kernel ----
__global__ __launch_bounds__(256) void span_fused_fp32_kernel(
    const float* __restrict__ emb, const float* __restrict__ w,
    const float* __restrict__ bias, const int* __restrict__ starts,
    const int* __restrict__ lengths, float* __restrict__ out)
{
    const int tid  = threadIdx.x;
    const int wv   = tid >> 6;
    const int lane = tid & 63;
    const int bi   = blockIdx.x & 7;
    const int rank = ((int)blockIdx.x >> 3) * 4 + wv;
    const int span = bi * NN + rank;
    const int start = starts[span];
    const int len   = lengths[span];

    const float* ebase = emb + (size_t)bi * SS * HH + (size_t)start * HH;
    const int h0 = lane * 4;
    float* orow = out + (size_t)span * (3 * HH);

    const float4 w0 = *reinterpret_cast<const float4*>(w + h0);
    const float4 w1 = *reinterpret_cast<const float4*>(w + h0 + 256);
    const float4 w2 = *reinterpret_cast<const float4*>(w + h0 + 512);
    const float bb = bias[0];

    float m = -INFINITY, ssum = 0.f;
    float4 a0 = make_float4(0.f, 0.f, 0.f, 0.f), a1 = a0, a2 = a0;

    const float* row = ebase;
    float4 v0 = *reinterpret_cast<const float4*>(row + h0);
    float4 v1 = *reinterpret_cast<const float4*>(row + h0 + 256);
    float4 v2 = *reinterpret_cast<const float4*>(row + h0 + 512);

    for (int t = 0; t <= len; ++t) {
        float4 n0, n1, n2;
        if (t < len) {
            const float* nr = row + HH;
            n0 = *reinterpret_cast<const float4*>(nr + h0);
            n1 = *reinterpret_cast<const float4*>(nr + h0 + 256);
            n2 = *reinterpret_cast<const float4*>(nr + h0 + 512);
        }
        float d = v0.x * w0.x + v0.y * w0.y + v0.z * w0.z + v0.w * w0.w
                + v1.x * w1.x + v1.y * w1.y + v1.z * w1.z + v1.w * w1.w
                + v2.x * w2.x + v2.y * w2.y + v2.z * w2.z + v2.w * w2.w;
        #pragma unroll
        for (int off = 32; off; off >>= 1) d += __shfl_xor(d, off);
        d += bb;
        if (d > m) {
            const float c = __expf(m - d);
            ssum *= c;
            a0.x *= c; a0.y *= c; a0.z *= c; a0.w *= c;
            a1.x *= c; a1.y *= c; a1.z *= c; a1.w *= c;
            a2.x *= c; a2.y *= c; a2.z *= c; a2.w *= c;
            m = d;
        }
        const float pt = __expf(d - m);
        ssum += pt;
        a0.x += pt * v0.x; a0.y += pt * v0.y; a0.z += pt * v0.z; a0.w += pt * v0.w;
        a1.x += pt * v1.x; a1.y += pt * v1.y; a1.z += pt * v1.z; a1.w += pt * v1.w;
        a2.x += pt * v2.x; a2.y += pt * v2.y; a2.z += pt * v2.z; a2.w += pt * v2.w;
        if (t == 0) {
            *reinterpret_cast<float4*>(orow + h0)       = v0;
            *reinterpret_cast<float4*>(orow + h0 + 256) = v1;
            *reinterpret_cast<float4*>(orow + h0 + 512) = v2;
        }
        if (t == len) {
            *reinterpret_cast<float4*>(orow + HH + h0)       = v0;
            *reinterpret_cast<float4*>(orow + HH + h0 + 256) = v1;
            *reinterpret_cast<float4*>(orow + HH + h0 + 512) = v2;
        }
        v0 = n0; v1 = n1; v2 = n2;
        row += HH;
    }
    const float inv = 1.f / ssum;
    a0.x *= inv; a0.y *= inv; a0.z *= inv; a0.w *= inv;
    a1.x *= inv; a1.y *= inv; a1.z *= inv; a1.w *= inv;
    a2.x *= inv; a2.y *= inv; a2.z *= inv; a2.w *= inv;
    *reinterpret_cast<float4*>(orow + 2 * HH + h0)       = a0;
    *reinterpret_cast<float4*>(orow + 2 * HH + h0 + 256) = a1;
    *reinterpret_cast<float4*>(orow + 2 * HH + h0 + 512) = a2;
}

extern "C" void kernel_launch(void* const* d_in, const int* in_sizes, int n_in,
                              void* d_out, int out_size, void* d_ws, size_t ws_size,
                              hipStream_t stream) {
    const float* emb     = (const float*)d_in[0];
    const float* w       = (const float*)d_in[1];
    const float* bias    = (const float*)d_in[2];
    const int*   starts  = (const int*)d_in[3];
    const int*   lengths = (const int*)d_in[4];
    float*       out     = (float*)d_out;

    const size_t ebf_bytes    = (size_t)BB * SS * HH * sizeof(unsigned short);
    const size_t scores_bytes = (size_t)BB * SS * sizeof(float);
    const size_t order_bytes  = (size_t)BB * NN * sizeof(int);

    if (ws_size >= ebf_bytes + scores_bytes + order_bytes) {
        unsigned short* ebf = (unsigned short*)d_ws;
        float* scores = (float*)((char*)d_ws + ebf_bytes);
        int*   order  = (int*)((char*)d_ws + ebf_bytes + scores_bytes);

        prep_kernel<<<dim3(1024 + BB), dim3(256), 0, stream>>>(
            emb, w, bias, starts, ebf, scores, order);
        span_bf16_kernel<<<dim3(BB * NN / 4), dim3(256), 0, stream>>>(
            ebf, scores, starts, lengths, order, out);
    } else {
        span_fused_fp32_kernel<<<dim3(BB * NN / 4), dim3(256), 0, stream>>>(
            emb, w, bias, starts, lengths, out);
    }
}